// Round 4
// baseline (385.870 us; speedup 1.0000x reference)
//
#include <hip/hip_runtime.h>
#include <stdint.h>

// ---------------------------------------------------------------------------
// CausalVAELayer forward, MI355X (gfx950). FP32 in / FP32 out.
// Internally: bf16 MFMA GEMMs, fp32 acc, bf16 intermediates.
// B=8,S=2048,D=1024,C=16,CD=64,L=1024. Tokens N=16384.
//
// ROUND 13:
// (a) cvt_x ELIMINATED: encoder GEMM reg-stages A directly from fp32 x
//     (global_load_dwordx4 at tile front -> MFMA region -> vmcnt(4) ->
//     v_cvt bf16 -> ds_write_b128 into other buffer). Same RNE bits as the
//     old f2b kernel; deletes 80 MB of HBM traffic + one launch.
// (b) K-loop: BOTH panels now stage 1-ahead into the OTHER buffer ->
//     no overwrite hazard -> ONE barrier + ONE vmcnt per tile, NO
//     block-wide lgkmcnt(0) drain (round-12 measured the drain serializing
//     LDS vs MFMA; first MFMA now starts on compiler's per-read lgkm waits).
//     Staging in-flight window = full tile (~2000 cy) >> HBM miss latency.
// (c) dag_init merged into cvt_weights (blockIdx 2112).
// XCD swizzle + ni-innermost epilogue kept (FETCH/WRITE verified ideal).
// ---------------------------------------------------------------------------

#define NTOK   16384
#define DIM    1024
#define NC     16
#define CD     64
#define NOUT_ELEMS 16777216  // NTOK*DIM

typedef float f32x4 __attribute__((ext_vector_type(4)));
typedef __bf16 bf16x8 __attribute__((ext_vector_type(8)));
typedef unsigned short u16x4 __attribute__((ext_vector_type(4)));
typedef unsigned short u16x8 __attribute__((ext_vector_type(8)));

__device__ float g_scal[3];    // [2]=dag_loss
__device__ float g_part[512];  // [0..256)=kl partials, [256..512)=recon partials

__device__ __forceinline__ float b2f(uint16_t u) {
  union { uint32_t i; float f; } v; v.i = ((uint32_t)u) << 16; return v.f;
}
__device__ __forceinline__ uint16_t f2b(float f) {
  union { float f; uint32_t i; } v; v.f = f;
  uint32_t x = v.i;
  return (uint16_t)((x + 0x7fffu + ((x >> 16) & 1u)) >> 16);  // RNE
}

__device__ __forceinline__ void gload_lds16(const uint16_t* g, uint16_t* l) {
  __builtin_amdgcn_global_load_lds(
      (const __attribute__((address_space(1))) void*)g,
      (__attribute__((address_space(3))) void*)l, 16, 0, 0);
}

// convert 8 fp32 -> 8 bf16 (RNE), 16B store
__device__ __forceinline__ void cvt8(const float* s, uint16_t* d) {
  const f32x4 a = *(const f32x4*)s;
  const f32x4 b = *(const f32x4*)(s + 4);
  u16x8 o;
  o[0]=f2b(a[0]); o[1]=f2b(a[1]); o[2]=f2b(a[2]); o[3]=f2b(a[3]);
  o[4]=f2b(b[0]); o[5]=f2b(b[1]); o[6]=f2b(b[2]); o[7]=f2b(b[3]);
  *(u16x8*)d = o;
}

// weights -> Wbf: [enc_w 2M | dec_w1 1M | dec_w2 1M | cw1 64K | cw2 64K].
// Block 2112 does the dag-loss init instead (merged dag_init).
__global__ __launch_bounds__(256) void cvt_weights_kernel(
    const float* __restrict__ ew, const float* __restrict__ d1,
    const float* __restrict__ d2, const float* __restrict__ c1,
    const float* __restrict__ c2, uint16_t* __restrict__ out,
    const float* __restrict__ dag_w)
{
  if (blockIdx.x == 2112) {
    const int t = threadIdx.x;
    g_part[t] = 0.f;
    g_part[256 + t] = 0.f;
    const int i2 = t >> 4, j2 = t & 15;
    const float v = (j2 < i2) ? log1pf(expf(dag_w[t])) : 0.f;
    float s = v;
#pragma unroll
    for (int m = 1; m < 64; m <<= 1) s += __shfl_xor(s, m);
    __shared__ float red[4];
    const int wave = t >> 6, lane = t & 63;
    if (lane == 0) red[wave] = s;
    __syncthreads();
    if (t == 0)
      g_scal[2] = red[0] + red[1] + red[2] + red[3] + 16.f;  // trace(expm)=C
    return;
  }
  const int i = blockIdx.x * 256 + threadIdx.x;  // elem8 idx, total 540672
  const float* src; uint16_t* dst; int off;
  if (i < 262144)      { src = ew; dst = out;           off = i; }
  else if (i < 393216) { src = d1; dst = out + 2097152; off = i - 262144; }
  else if (i < 524288) { src = d2; dst = out + 3145728; off = i - 393216; }
  else if (i < 532480) { src = c1; dst = out + 4194304; off = i - 524288; }
  else                 { src = c2; dst = out + 4259840; off = i - 532480; }
  cvt8(src + (size_t)off * 8, dst + (size_t)off * 8);
}

// ---------------------------------------------------------------------------
// Stage one 128-row half of a [256 x 64] bf16 K-tile panel into an LDS region
// (32 KB, rows of 128 B, 16B-chunk XOR swizzle: logical chunk c of row r at
// physical slot c ^ (r&7)). 2 global_load_lds (width 16) per wave.
// 512 threads: sr = tid>>3 in [0,64), pc = tid&7.
// ---------------------------------------------------------------------------
__device__ __forceinline__ void stage_half(
    const uint16_t* __restrict__ G, uint16_t* L, int h, int lda,
    int sr, int pc, int wave)
{
#pragma unroll
  for (int i = 0; i < 2; ++i) {
    const int r = h * 128 + i * 64 + sr;
    gload_lds16(G + (size_t)r * lda + (size_t)((pc ^ (sr & 7)) * 8),
                (uint16_t*)((char*)L + h * 16384 + i * 8192 + wave * 1024));
  }
}

// ---------------------------------------------------------------------------
// 256x256-tile pipelined GEMM: C[m,n] = sum_k A[m,k]*W[n,k] + bias[n].
// 8 waves (2 M x 4 N), per-wave 128x64 output, acc[8][4] f32x4.
// LDS: 2 buffers x (A 32KB + B 32KB) = 128 KiB. K multiple of 64.
// TA=float: A is fp32, reg-staged + converted to bf16 in-kernel (encoder).
// SPLIT: epilogue routes cols [0,1024)->C0, [1024,2048)->C1 (encoder).
// RECON: epilogue accumulates sum((v - Xref)^2) into g_part (spread).
// ---------------------------------------------------------------------------
template<typename TA, typename TC, bool SPLIT, bool RECON>
__global__ __launch_bounds__(512, 2) void gemm256_kernel(
    const TA* __restrict__ A, const uint16_t* __restrict__ Wm,
    const float* __restrict__ bias, TC* __restrict__ C0, TC* __restrict__ C1,
    const float* __restrict__ Xref,
    int K, int lda, int ldw, int ldc)
{
  constexpr bool CVTA = (sizeof(TA) == 4);
  __shared__ __align__(16) uint16_t lds[65536];  // 128 KiB

  const int tid  = threadIdx.x;
  const int wave = tid >> 6;
  const int lane = tid & 63;
  const int q    = lane >> 4;
  const int r16  = lane & 15;
  const int wm   = wave >> 2;   // 0..1
  const int wn   = wave & 3;    // 0..3
  const int sr   = tid >> 3;    // 0..63
  const int pc   = tid & 7;

  // XCD-aware bijective chunked swizzle, bn-FASTEST within each chunk:
  // blocks on one XCD share bm A-panels (A fetched once into that XCD's L2).
  const int gx  = gridDim.x;
  const int gy  = gridDim.y;
  const int nwg = gx * gy;
  const int o   = blockIdx.y * gx + blockIdx.x;
  const int w   = (o & 7) * (nwg >> 3) + (o >> 3);
  const int bn  = (w & (gy - 1)) * 256;
  const int bm  = (w >> __builtin_ctz(gy)) * 256;

  const TA*       Abase = A  + (size_t)bm * lda;
  const uint16_t* Wb    = Wm + (size_t)bn * ldw;

  const int T = K >> 6;  // K-tiles of 64

  // ---- prologue: stage tile0 -> buf0 ----
  if constexpr (CVTA) {
    f32x4 pLo[4], pHi[4];
#pragma unroll
    for (int j = 0; j < 4; ++j) {
      const int r = j * 64 + sr;
      const float* src = (const float*)Abase + (size_t)r * lda + (pc ^ (r & 7)) * 8;
      pLo[j] = *(const f32x4*)src;
      pHi[j] = *(const f32x4*)(src + 4);
    }
    stage_half(Wb, lds + 16384, 0, ldw, sr, pc, wave);
    stage_half(Wb, lds + 16384, 1, ldw, sr, pc, wave);
    asm volatile("s_waitcnt vmcnt(4)" ::: "memory");
#pragma unroll
    for (int j = 0; j < 4; ++j) {
      const int r = j * 64 + sr;
      bf16x8 ov;
#pragma unroll
      for (int e = 0; e < 4; ++e) { ov[e] = (__bf16)pLo[j][e]; ov[4 + e] = (__bf16)pHi[j][e]; }
      *(bf16x8*)(lds + r * 64 + pc * 8) = ov;
    }
    asm volatile("s_waitcnt vmcnt(0) lgkmcnt(0)" ::: "memory");
  } else {
    stage_half((const uint16_t*)Abase, lds, 0, lda, sr, pc, wave);
    stage_half((const uint16_t*)Abase, lds, 1, lda, sr, pc, wave);
    stage_half(Wb, lds + 16384, 0, ldw, sr, pc, wave);
    stage_half(Wb, lds + 16384, 1, ldw, sr, pc, wave);
    asm volatile("s_waitcnt vmcnt(0)" ::: "memory");
  }
  __builtin_amdgcn_s_barrier();

  f32x4 acc[8][4] = {};
  const int cxa = r16 & 7;
  const int c0  = (q ^ cxa) * 8;          // elems, ks=0 chunk
  const int c1  = ((4 + q) ^ cxa) * 8;    // elems, ks=1 chunk

  for (int t = 0; t < T; ++t) {
    uint16_t* As  = lds + (t & 1) * 32768;
    uint16_t* Bs  = As + 16384;
    uint16_t* Asn = lds + ((t & 1) ^ 1) * 32768;
    uint16_t* Bsn = Asn + 16384;
    const bool pf = (t + 1 < T);

    // ---- front: issue tile t+1 staging into the OTHER buffer ----
    f32x4 aLo[4], aHi[4];
    if (pf) {
      if constexpr (CVTA) {
#pragma unroll
        for (int j = 0; j < 4; ++j) {
          const int r = j * 64 + sr;
          const float* src = (const float*)Abase + (size_t)r * lda
                           + (t + 1) * 64 + (pc ^ (r & 7)) * 8;
          aLo[j] = *(const f32x4*)src;
          aHi[j] = *(const f32x4*)(src + 4);
        }
      } else {
        stage_half((const uint16_t*)Abase + (size_t)(t + 1) * 64, Asn, 0, lda, sr, pc, wave);
        stage_half((const uint16_t*)Abase + (size_t)(t + 1) * 64, Asn, 1, lda, sr, pc, wave);
      }
      stage_half(Wb + (size_t)(t + 1) * 64, Bsn, 0, ldw, sr, pc, wave);
      stage_half(Wb + (size_t)(t + 1) * 64, Bsn, 1, ldw, sr, pc, wave);
    }

    const uint16_t* a_rd = As + (wm * 128 + r16) * 64;
    const uint16_t* b_rd = Bs + (wn * 64  + r16) * 64;

    // ---- reads + MFMA, no block-wide drain (compiler inserts counted
    //      lgkm waits per dependency) ----
    bf16x8 bfr[4][2], af0[2][2];
#pragma unroll
    for (int ni = 0; ni < 4; ++ni) {
      bfr[ni][0] = *(const bf16x8*)(b_rd + ni * 1024 + c0);
      bfr[ni][1] = *(const bf16x8*)(b_rd + ni * 1024 + c1);
    }
#pragma unroll
    for (int mi2 = 0; mi2 < 2; ++mi2) {
      af0[mi2][0] = *(const bf16x8*)(a_rd + mi2 * 1024 + c0);
      af0[mi2][1] = *(const bf16x8*)(a_rd + mi2 * 1024 + c1);
    }

    __builtin_amdgcn_s_setprio(1);
#pragma unroll
    for (int ks = 0; ks < 2; ++ks)
#pragma unroll
      for (int mi2 = 0; mi2 < 2; ++mi2)
#pragma unroll
        for (int ni = 0; ni < 4; ++ni)
          acc[mi2][ni] = __builtin_amdgcn_mfma_f32_16x16x32_bf16(
              af0[mi2][ks], bfr[ni][ks], acc[mi2][ni], 0, 0, 0);

    // mi{2..7}: one-ahead pipelined ds_reads interleaved with MFMA
    bf16x8 aP0 = *(const bf16x8*)(a_rd + 2 * 1024 + c0);
    bf16x8 aP1 = *(const bf16x8*)(a_rd + 2 * 1024 + c1);
#pragma unroll
    for (int mi = 2; mi < 8; ++mi) {
      const bf16x8 a0 = aP0, a1 = aP1;
      if (mi < 7) {
        aP0 = *(const bf16x8*)(a_rd + (mi + 1) * 1024 + c0);
        aP1 = *(const bf16x8*)(a_rd + (mi + 1) * 1024 + c1);
      }
#pragma unroll
      for (int ni = 0; ni < 4; ++ni)
        acc[mi][ni] = __builtin_amdgcn_mfma_f32_16x16x32_bf16(
            a0, bfr[ni][0], acc[mi][ni], 0, 0, 0);
#pragma unroll
      for (int ni = 0; ni < 4; ++ni)
        acc[mi][ni] = __builtin_amdgcn_mfma_f32_16x16x32_bf16(
            a1, bfr[ni][1], acc[mi][ni], 0, 0, 0);
    }
    __builtin_amdgcn_s_setprio(0);

    // ---- boundary: land tile t+1, one barrier ----
    if (pf) {
      if constexpr (CVTA) {
        asm volatile("s_waitcnt vmcnt(4)" ::: "memory");  // A fp32 regs ready
#pragma unroll
        for (int j = 0; j < 4; ++j) {
          const int r = j * 64 + sr;
          bf16x8 ov;
#pragma unroll
          for (int e = 0; e < 4; ++e) { ov[e] = (__bf16)aLo[j][e]; ov[4 + e] = (__bf16)aHi[j][e]; }
          *(bf16x8*)(Asn + r * 64 + pc * 8) = ov;
        }
        asm volatile("s_waitcnt vmcnt(0) lgkmcnt(0)" ::: "memory");  // B landed, writes visible
      } else {
        asm volatile("s_waitcnt vmcnt(0)" ::: "memory");
      }
    }
    __builtin_amdgcn_s_barrier();
  }

  // ---- epilogue. C/D layout: col = lane&15, row = (lane>>4)*4 + reg. ----
  // ni innermost: each quarter-wave completes a 128B line in 4 consecutive
  // 32B chunks -> good write-combining, no partial-line RMW.
  TC* Cq = C0;
  int cb = bn;
  if constexpr (SPLIT) {
    if (bn >= 1024) { Cq = C1; cb = bn - 1024; }
  }
  float bv[4];
#pragma unroll
  for (int ni = 0; ni < 4; ++ni) bv[ni] = bias[bn + wn * 64 + ni * 16 + r16];

  float rsum = 0.f;
#pragma unroll
  for (int mi = 0; mi < 8; ++mi) {
    const int rbase = bm + wm * 128 + mi * 16 + q * 4;
#pragma unroll
    for (int r = 0; r < 4; ++r) {
      const size_t rowoff = (size_t)(rbase + r) * ldc + cb;
#pragma unroll
      for (int ni = 0; ni < 4; ++ni) {
        const int loc = wn * 64 + ni * 16 + r16;
        const float v = acc[mi][ni][r] + bv[ni];
        if constexpr (sizeof(TC) == 2)
          Cq[rowoff + loc] = f2b(v);
        else
          Cq[rowoff + loc] = v;
        if constexpr (RECON) {
          const float dd = v - Xref[rowoff + loc];
          rsum += dd * dd;
        }
      }
    }
  }
  if constexpr (RECON) {
#pragma unroll
    for (int m = 1; m < 64; m <<= 1) rsum += __shfl_xor(rsum, m);
    __shared__ float redR[8];
    if (lane == 0) redR[wave] = rsum;
    __syncthreads();
    if (tid == 0) {
      float s = 0.f;
#pragma unroll
      for (int w2 = 0; w2 < 8; ++w2) s += redR[w2];
      atomicAdd(&g_part[256 + (w & 255)], s);
    }
  }
}

// ---------------------------------------------------------------------------
// Fused concept transform: z_t = ReLU(LN(zc@cw1^T + cb1)) @ cw2^T + cb2.
// Block = (concept c, 128-token tile), in-place on z ([NTOK,1024] bf16).
// ---------------------------------------------------------------------------
__global__ __launch_bounds__(256) void concept_fused_kernel(
    uint16_t* __restrict__ z, const uint16_t* __restrict__ c1b,
    const uint16_t* __restrict__ c2b, const float* __restrict__ cb1,
    const float* __restrict__ cg, const float* __restrict__ cbt,
    const float* __restrict__ cb2)
{
  __shared__ __align__(16) uint16_t Az[128 * 64];   // zc tile, then t tile
  __shared__ __align__(16) uint16_t W1s[64 * 64];
  __shared__ __align__(16) uint16_t W2s[64 * 64];

  const int tid  = threadIdx.x;
  const int wave = tid >> 6;
  const int lane = tid & 63;
  const int q    = lane >> 4;
  const int r16  = lane & 15;
  const int c    = blockIdx.y;
  const int m0   = blockIdx.x * 128;

  const int lr = tid >> 3;
  const int pc = tid & 7;

#pragma unroll
  for (int i = 0; i < 4; ++i) {
    const int r = i * 32 + lr;
    const int gc = pc ^ (r & 7);
    gload_lds16(z + (size_t)(m0 + r) * DIM + c * 64 + gc * 8,
                (uint16_t*)((char*)Az + i * 4096 + wave * 1024));
  }
#pragma unroll
  for (int i = 0; i < 2; ++i) {
    const int r = i * 32 + lr;
    const int gc = pc ^ (r & 7);
    gload_lds16(c1b + (size_t)c * 4096 + r * 64 + gc * 8,
                (uint16_t*)((char*)W1s + i * 4096 + wave * 1024));
    gload_lds16(c2b + (size_t)c * 4096 + r * 64 + gc * 8,
                (uint16_t*)((char*)W2s + i * 4096 + wave * 1024));
  }
  __syncthreads();

  // MFMA1: t = zc @ cw1^T
  f32x4 acc[2][4] = {};
#pragma unroll
  for (int ks = 0; ks < 2; ++ks) {
    bf16x8 af[2], wf[4];
#pragma unroll
    for (int mi = 0; mi < 2; ++mi) {
      const int row = wave * 32 + mi * 16 + r16;
      af[mi] = *(const bf16x8*)(Az + row * 64 + ((ks * 4 + q) ^ (row & 7)) * 8);
    }
#pragma unroll
    for (int ni = 0; ni < 4; ++ni) {
      const int d = ni * 16 + r16;
      wf[ni] = *(const bf16x8*)(W1s + d * 64 + ((ks * 4 + q) ^ (d & 7)) * 8);
    }
#pragma unroll
    for (int mi = 0; mi < 2; ++mi)
#pragma unroll
      for (int ni = 0; ni < 4; ++ni)
        acc[mi][ni] = __builtin_amdgcn_mfma_f32_16x16x32_bf16(
            af[mi], wf[ni], acc[mi][ni], 0, 0, 0);
  }

  float b1v[4], cgv[4], cbv[4], b2v[4];
#pragma unroll
  for (int ni = 0; ni < 4; ++ni) {
    const int cn = ni * 16 + r16;
    b1v[ni] = cb1[c * 64 + cn];
    cgv[ni] = cg[c * 64 + cn];
    cbv[ni] = cbt[c * 64 + cn];
    b2v[ni] = cb2[c * 64 + cn];
  }
#pragma unroll
  for (int mi = 0; mi < 2; ++mi) {
#pragma unroll
    for (int r = 0; r < 4; ++r) {
      float s1 = 0.f, s2 = 0.f;
#pragma unroll
      for (int ni = 0; ni < 4; ++ni) {
        const float v = acc[mi][ni][r] + b1v[ni];
        acc[mi][ni][r] = v;
        s1 += v; s2 += v * v;
      }
#pragma unroll
      for (int m = 1; m < 16; m <<= 1) {
        s1 += __shfl_xor(s1, m);
        s2 += __shfl_xor(s2, m);
      }
      const float mean = s1 * (1.f / 64.f);
      const float var  = s2 * (1.f / 64.f) - mean * mean;
      const float rs   = rsqrtf(var + 1e-5f);
      const int row = wave * 32 + mi * 16 + q * 4 + r;
#pragma unroll
      for (int ni = 0; ni < 4; ++ni) {
        const float y = fmaxf((acc[mi][ni][r] - mean) * rs * cgv[ni] + cbv[ni], 0.f);
        const int cn = ni * 16 + r16;
        Az[row * 64 + (((cn >> 3) ^ (row & 7)) * 8) + (cn & 7)] = f2b(y);
      }
    }
  }
  __syncthreads();

  // MFMA2: zt = t @ cw2^T
  f32x4 acc2[2][4] = {};
#pragma unroll
  for (int ks = 0; ks < 2; ++ks) {
    bf16x8 af[2], wf[4];
#pragma unroll
    for (int mi = 0; mi < 2; ++mi) {
      const int row = wave * 32 + mi * 16 + r16;
      af[mi] = *(const bf16x8*)(Az + row * 64 + ((ks * 4 + q) ^ (row & 7)) * 8);
    }
#pragma unroll
    for (int ni = 0; ni < 4; ++ni) {
      const int d = ni * 16 + r16;
      wf[ni] = *(const bf16x8*)(W2s + d * 64 + ((ks * 4 + q) ^ (d & 7)) * 8);
    }
#pragma unroll
    for (int mi = 0; mi < 2; ++mi)
#pragma unroll
      for (int ni = 0; ni < 4; ++ni)
        acc2[mi][ni] = __builtin_amdgcn_mfma_f32_16x16x32_bf16(
            af[mi], wf[ni], acc2[mi][ni], 0, 0, 0);
  }

#pragma unroll
  for (int mi = 0; mi < 2; ++mi)
#pragma unroll
    for (int ni = 0; ni < 4; ++ni) {
      const int cn = ni * 16 + r16;
#pragma unroll
      for (int r = 0; r < 4; ++r) {
        const int row = wave * 32 + mi * 16 + q * 4 + r;
        z[(size_t)(m0 + row) * DIM + c * 64 + cn] = f2b(acc2[mi][ni][r] + b2v[ni]);
      }
    }
}

// ---------------------------------------------------------------------------
// Fused: encoder LN (stats over the 2048-wide [mu|lv] row) + KL partials
// + causal transform. One block (256 thr) per token.
// ---------------------------------------------------------------------------
__global__ __launch_bounds__(256) void kl_causal_kernel(
    const uint16_t* __restrict__ lv, uint16_t* __restrict__ mu,
    const float* __restrict__ g, const float* __restrict__ b,
    const float* __restrict__ dag_w)
{
  __shared__ __align__(16) float zsh[1024];
  __shared__ float dg[256];
  __shared__ float red[8];
  __shared__ float red2[4];
  const int tid = threadIdx.x;
  const int tok = blockIdx.x;
  const int e0  = tid * 4;

  {
    const int di = tid >> 4, dj = tid & 15;
    dg[tid] = (dj < di) ? log1pf(expf(dag_w[tid])) : 0.f;
  }

  const uint16_t* lvp = lv + (size_t)tok * 1024;
  uint16_t*       mup = mu + (size_t)tok * 1024;

  const u16x4 m4 = *(const u16x4*)(mup + e0);
  const u16x4 l4 = *(const u16x4*)(lvp + e0);
  float xm[4], xl[4];
  float s1 = 0.f, s2 = 0.f;
#pragma unroll
  for (int k = 0; k < 4; ++k) {
    xm[k] = b2f(m4[k]);
    xl[k] = b2f(l4[k]);
    s1 += xm[k] + xl[k];
    s2 += xm[k] * xm[k] + xl[k] * xl[k];
  }
#pragma unroll
  for (int m = 1; m < 64; m <<= 1) {
    s1 += __shfl_xor(s1, m);
    s2 += __shfl_xor(s2, m);
  }
  const int wave = tid >> 6, lane = tid & 63;
  if (lane == 0) { red[wave] = s1; red[4 + wave] = s2; }
  __syncthreads();
  s1 = red[0] + red[1] + red[2] + red[3];
  s2 = red[4] + red[5] + red[6] + red[7];
  const float mean = s1 * (1.f / 2048.f);
  const float var  = s2 * (1.f / 2048.f) - mean * mean;
  const float rs   = rsqrtf(var + 1e-5f);

  const f32x4 g4m = *(const f32x4*)(g + e0);
  const f32x4 b4m = *(const f32x4*)(b + e0);
  const f32x4 g4l = *(const f32x4*)(g + 1024 + e0);
  const f32x4 b4l = *(const f32x4*)(b + 1024 + e0);
  float kl = 0.f;
  f32x4 z;
#pragma unroll
  for (int k = 0; k < 4; ++k) {
    z[k] = (xm[k] - mean) * rs * g4m[k] + b4m[k];
    const float y = (xl[k] - mean) * rs * g4l[k] + b4l[k];
    kl += 1.f + y - z[k] * z[k] - expf(y);
  }
  *(f32x4*)(zsh + e0) = z;
#pragma unroll
  for (int m = 1; m < 64; m <<= 1) kl += __shfl_xor(kl, m);
  if (lane == 0) red2[wave] = kl;
  __syncthreads();
  if (tid == 0)
    atomicAdd(&g_part[tok & 255], red2[0] + red2[1] + red2[2] + red2[3]);

  const int i  = e0 >> 6;
  const int d0 = e0 & 63;
  f32x4 s = *(const f32x4*)(zsh + e0);
  for (int j = 0; j < i; ++j) {
    const float w = dg[i * 16 + j];
    const f32x4 zj = *(const f32x4*)(zsh + j * 64 + d0);
    s[0] += w * zj[0]; s[1] += w * zj[1]; s[2] += w * zj[2]; s[3] += w * zj[3];
  }
  u16x4 o;
#pragma unroll
  for (int k = 0; k < 4; ++k) o[k] = f2b(s[k]);
  *(u16x4*)(mup + e0) = o;
}

// ---------------------------------------------------------------------------
// LayerNorm(1024) + ReLU, in-place on bf16 rows, one block (256 thr) per row.
// ---------------------------------------------------------------------------
__global__ __launch_bounds__(256) void ln_relu_kernel(
    uint16_t* __restrict__ data, const float* __restrict__ g,
    const float* __restrict__ b)
{
  const int tid = threadIdx.x;
  const int e0  = tid * 4;
  uint16_t* p = data + (size_t)blockIdx.x * 1024;

  const u16x4 v4 = *(const u16x4*)(p + e0);
  float x[4];
  float s1 = 0.f, s2 = 0.f;
#pragma unroll
  for (int k = 0; k < 4; ++k) {
    x[k] = b2f(v4[k]);
    s1 += x[k];
    s2 += x[k] * x[k];
  }
#pragma unroll
  for (int m = 1; m < 64; m <<= 1) {
    s1 += __shfl_xor(s1, m);
    s2 += __shfl_xor(s2, m);
  }
  __shared__ float red[8];
  const int wave = tid >> 6, lane = tid & 63;
  if (lane == 0) { red[wave] = s1; red[4 + wave] = s2; }
  __syncthreads();
  s1 = red[0] + red[1] + red[2] + red[3];
  s2 = red[4] + red[5] + red[6] + red[7];
  const float mean = s1 * (1.f / 1024.f);
  const float var  = s2 * (1.f / 1024.f) - mean * mean;
  const float rs   = rsqrtf(var + 1e-5f);

  const f32x4 g4 = *(const f32x4*)(g + e0);
  const f32x4 b4 = *(const f32x4*)(b + e0);
  u16x4 o;
#pragma unroll
  for (int k = 0; k < 4; ++k) {
    const float y = (x[k] - mean) * rs * g4[k] + b4[k];
    o[k] = f2b(fmaxf(y, 0.f));
  }
  *(u16x4*)(p + e0) = o;
}

// ---------------------------------------------------------------------------
// finalize: sum the 256+256 partial slots, emit the 4 loss scalars.
// ---------------------------------------------------------------------------
__global__ __launch_bounds__(256) void finalize_kernel(float* __restrict__ out_tail)
{
  const int tid = threadIdx.x;
  float kl = g_part[tid];
  float rc = g_part[256 + tid];
#pragma unroll
  for (int m = 1; m < 64; m <<= 1) {
    kl += __shfl_xor(kl, m);
    rc += __shfl_xor(rc, m);
  }
  __shared__ float red[8];
  const int wave = tid >> 6, lane = tid & 63;
  if (lane == 0) { red[wave] = kl; red[4 + wave] = rc; }
  __syncthreads();
  if (tid == 0) {
    const float kls = red[0] + red[1] + red[2] + red[3];
    const float rcs = red[4] + red[5] + red[6] + red[7];
    const float kl_l   = -0.5f * kls * (1.f / (16384.f * 1024.f));
    const float recon  = rcs * (1.f / 16777216.f);
    const float dagl   = g_scal[2];
    out_tail[0] = recon + 0.3f * kl_l + 1.0f * dagl;
    out_tail[1] = kl_l;
    out_tail[2] = recon;
    out_tail[3] = dagl;
  }
}

// ---------------------------------------------------------------------------
extern "C" void kernel_launch(void* const* d_in, const int* in_sizes, int n_in,
                              void* d_out, int out_size, void* d_ws, size_t ws_size,
                              hipStream_t stream) {
  const float* x      = (const float*)d_in[0];
  const float* enc_w  = (const float*)d_in[1];
  const float* enc_b  = (const float*)d_in[2];
  const float* enc_g  = (const float*)d_in[3];
  const float* enc_bt = (const float*)d_in[4];
  const float* dag_w  = (const float*)d_in[5];
  const float* cw1    = (const float*)d_in[6];
  const float* cb1    = (const float*)d_in[7];
  const float* cg     = (const float*)d_in[8];
  const float* cbt    = (const float*)d_in[9];
  const float* cw2    = (const float*)d_in[10];
  const float* cb2    = (const float*)d_in[11];
  const float* dec_w1 = (const float*)d_in[12];
  const float* dec_b1 = (const float*)d_in[13];
  const float* dec_g  = (const float*)d_in[14];
  const float* dec_bt = (const float*)d_in[15];
  const float* dec_w2 = (const float*)d_in[16];
  const float* dec_b2 = (const float*)d_in[17];

  uint16_t* S    = (uint16_t*)d_ws;                       // [16384x1024] bf16, 32 MiB
  uint16_t* Wbf  = (uint16_t*)((char*)d_ws + (size_t)NTOK * DIM * 2);
  uint16_t* ewb  = Wbf;                                   // enc_w   2,097,152
  uint16_t* d1b  = Wbf + 2097152;                         // dec_w1  1,048,576
  uint16_t* d2b  = Wbf + 3145728;                         // dec_w2  1,048,576
  uint16_t* c1b  = Wbf + 4194304;                         // cw1       65,536
  uint16_t* c2b  = Wbf + 4259840;                         // cw2       65,536

  uint16_t* Obf  = (uint16_t*)d_out;                      // bf16 scratch (lower half)
  float*    O    = (float*)d_out;                         // final fp32 x_recon + losses

  // 1. weights -> bf16 (+ dag init in block 2112)
  cvt_weights_kernel<<<2113, 256, 0, stream>>>(
      enc_w, dec_w1, dec_w2, cw1, cw2, Wbf, dag_w);

  // 2. encoder GEMM (A = fp32 x, converted in-kernel; split epilogue):
  //    mu -> Obf, lv -> S
  gemm256_kernel<float, uint16_t, true, false>
      <<<dim3(64, 8, 1), 512, 0, stream>>>(
      x, ewb, enc_b, Obf, S, nullptr, DIM, DIM, DIM, DIM);

  // 3. fused LN + KL + causal: z_causal overwrites mu in Obf
  kl_causal_kernel<<<NTOK, 256, 0, stream>>>(S, Obf, enc_g, enc_bt, dag_w);

  // 4. fused concept transform (concept1 + LN64 + ReLU + concept2), in-place
  concept_fused_kernel<<<dim3(128, 16, 1), 256, 0, stream>>>(
      Obf, c1b, c2b, cb1, cg, cbt, cb2);

  // 5. decoder GEMM1: d_pre = z_t @ dec_w1^T + dec_b1 -> S
  gemm256_kernel<uint16_t, uint16_t, false, false>
      <<<dim3(64, 4, 1), 512, 0, stream>>>(
      Obf, d1b, dec_b1, S, S, nullptr, DIM, DIM, DIM, DIM);

  // 6. decoder LN + ReLU (in-place on S)
  ln_relu_kernel<<<NTOK, 256, 0, stream>>>(S, dec_g, dec_bt);

  // 7. decoder GEMM2 + fused recon: x_recon = d @ dec_w2^T + dec_b2 -> O (fp32)
  gemm256_kernel<uint16_t, float, false, true>
      <<<dim3(64, 4, 1), 512, 0, stream>>>(
      S, d2b, dec_b2, O, O, x, DIM, DIM, DIM, DIM);

  // 8. final scalars
  finalize_kernel<<<1, 256, 0, stream>>>(O + (size_t)NOUT_ELEMS);
}

// Round 5
// 370.972 us; speedup vs baseline: 1.0402x; 1.0402x over previous
//
#include <hip/hip_runtime.h>
#include <stdint.h>

// ---------------------------------------------------------------------------
// CausalVAELayer forward, MI355X (gfx950). FP32 in / FP32 out.
// Internally: bf16 MFMA GEMMs, fp32 acc, bf16 intermediates.
// B=8,S=2048,D=1024,C=16,CD=64,L=1024. Tokens N=16384.
//
// ROUND 14: REVERT gemm256 K-loop + cvt_x to the round-11 bytes (best total
// 376.7; rounds 12/13's schedule edits both regressed). Keep r13's merged
// dag_init in cvt_weights. NEW: kl_causal + ln_relu rewritten per G13 --
// 2 tokens(rows) per block, u16x8 16B loads/stores (was 8B), per-token
// 2-wave reduce. Same f2b RNE numerics.
// ---------------------------------------------------------------------------

#define NTOK   16384
#define DIM    1024
#define NC     16
#define CD     64
#define NOUT_ELEMS 16777216  // NTOK*DIM

typedef float f32x4 __attribute__((ext_vector_type(4)));
typedef __bf16 bf16x8 __attribute__((ext_vector_type(8)));
typedef unsigned short u16x4 __attribute__((ext_vector_type(4)));
typedef unsigned short u16x8 __attribute__((ext_vector_type(8)));

__device__ float g_scal[3];    // [2]=dag_loss
__device__ float g_part[512];  // [0..256)=kl partials, [256..512)=recon partials

__device__ __forceinline__ float b2f(uint16_t u) {
  union { uint32_t i; float f; } v; v.i = ((uint32_t)u) << 16; return v.f;
}
__device__ __forceinline__ uint16_t f2b(float f) {
  union { float f; uint32_t i; } v; v.f = f;
  uint32_t x = v.i;
  return (uint16_t)((x + 0x7fffu + ((x >> 16) & 1u)) >> 16);  // RNE
}

__device__ __forceinline__ void gload_lds16(const uint16_t* g, uint16_t* l) {
  __builtin_amdgcn_global_load_lds(
      (const __attribute__((address_space(1))) void*)g,
      (__attribute__((address_space(3))) void*)l, 16, 0, 0);
}

// convert 8 fp32 -> 8 bf16 (RNE), 16B store
__device__ __forceinline__ void cvt8(const float* s, uint16_t* d) {
  const f32x4 a = *(const f32x4*)s;
  const f32x4 b = *(const f32x4*)(s + 4);
  u16x8 o;
  o[0]=f2b(a[0]); o[1]=f2b(a[1]); o[2]=f2b(a[2]); o[3]=f2b(a[3]);
  o[4]=f2b(b[0]); o[5]=f2b(b[1]); o[6]=f2b(b[2]); o[7]=f2b(b[3]);
  *(u16x8*)d = o;
}

__global__ __launch_bounds__(256) void cvt_x_kernel(
    const float* __restrict__ src, uint16_t* __restrict__ dst)
{
  const int i = blockIdx.x * 256 + threadIdx.x;
  cvt8(src + (size_t)i * 8, dst + (size_t)i * 8);
}

// weights -> Wbf: [enc_w 2M | dec_w1 1M | dec_w2 1M | cw1 64K | cw2 64K].
// Block 2112 does the dag-loss init instead (merged dag_init).
__global__ __launch_bounds__(256) void cvt_weights_kernel(
    const float* __restrict__ ew, const float* __restrict__ d1,
    const float* __restrict__ d2, const float* __restrict__ c1,
    const float* __restrict__ c2, uint16_t* __restrict__ out,
    const float* __restrict__ dag_w)
{
  if (blockIdx.x == 2112) {
    const int t = threadIdx.x;
    g_part[t] = 0.f;
    g_part[256 + t] = 0.f;
    const int i2 = t >> 4, j2 = t & 15;
    const float v = (j2 < i2) ? log1pf(expf(dag_w[t])) : 0.f;
    float s = v;
#pragma unroll
    for (int m = 1; m < 64; m <<= 1) s += __shfl_xor(s, m);
    __shared__ float red[4];
    const int wave = t >> 6, lane = t & 63;
    if (lane == 0) red[wave] = s;
    __syncthreads();
    if (t == 0)
      g_scal[2] = red[0] + red[1] + red[2] + red[3] + 16.f;  // trace(expm)=C
    return;
  }
  const int i = blockIdx.x * 256 + threadIdx.x;  // elem8 idx, total 540672
  const float* src; uint16_t* dst; int off;
  if (i < 262144)      { src = ew; dst = out;           off = i; }
  else if (i < 393216) { src = d1; dst = out + 2097152; off = i - 262144; }
  else if (i < 524288) { src = d2; dst = out + 3145728; off = i - 393216; }
  else if (i < 532480) { src = c1; dst = out + 4194304; off = i - 524288; }
  else                 { src = c2; dst = out + 4259840; off = i - 532480; }
  cvt8(src + (size_t)off * 8, dst + (size_t)off * 8);
}

// ---------------------------------------------------------------------------
// Stage one 128-row half of a [256 x 64] bf16 K-tile panel into an LDS region
// (32 KB, rows of 128 B, 16B-chunk XOR swizzle: logical chunk c of row r at
// physical slot c ^ (r&7)). 2 global_load_lds (width 16) per wave.
// 512 threads: sr = tid>>3 in [0,64), pc = tid&7.
// ---------------------------------------------------------------------------
__device__ __forceinline__ void stage_half(
    const uint16_t* __restrict__ G, uint16_t* L, int h, int lda,
    int sr, int pc, int wave)
{
#pragma unroll
  for (int i = 0; i < 2; ++i) {
    const int r = h * 128 + i * 64 + sr;
    gload_lds16(G + (size_t)r * lda + (size_t)((pc ^ (sr & 7)) * 8),
                (uint16_t*)((char*)L + h * 16384 + i * 8192 + wave * 1024));
  }
}

// ---------------------------------------------------------------------------
// 256x256-tile pipelined GEMM (round-11 verified): 4 phases, vmcnt(4),
// XCD-chunked bn-fastest swizzle, ni-innermost epilogue.
// ---------------------------------------------------------------------------
template<typename TC, bool SPLIT, bool RECON>
__global__ __launch_bounds__(512, 2) void gemm256_kernel(
    const uint16_t* __restrict__ A, const uint16_t* __restrict__ Wm,
    const float* __restrict__ bias, TC* __restrict__ C0, TC* __restrict__ C1,
    const float* __restrict__ Xref,
    int K, int lda, int ldw, int ldc)
{
  __shared__ __align__(16) uint16_t lds[65536];  // 128 KiB

  const int tid  = threadIdx.x;
  const int wave = tid >> 6;
  const int lane = tid & 63;
  const int q    = lane >> 4;
  const int r16  = lane & 15;
  const int wm   = wave >> 2;   // 0..1
  const int wn   = wave & 3;    // 0..3
  const int sr   = tid >> 3;    // 0..63
  const int pc   = tid & 7;

  const int gx  = gridDim.x;
  const int gy  = gridDim.y;
  const int nwg = gx * gy;
  const int o   = blockIdx.y * gx + blockIdx.x;
  const int w   = (o & 7) * (nwg >> 3) + (o >> 3);
  const int bn  = (w & (gy - 1)) * 256;
  const int bm  = (w >> __builtin_ctz(gy)) * 256;

  const uint16_t* Ab = A  + (size_t)bm * lda;
  const uint16_t* Wb = Wm + (size_t)bn * ldw;

  const int T = K >> 6;  // K-tiles of 64

  // ---- prologue: tile0 A+B -> buf0; tile1 B -> buf1 ----
  stage_half(Ab,      lds,                 0, lda, sr, pc, wave);
  stage_half(Ab,      lds,                 1, lda, sr, pc, wave);
  stage_half(Wb,      lds + 16384,         0, ldw, sr, pc, wave);
  stage_half(Wb,      lds + 16384,         1, ldw, sr, pc, wave);
  if (T > 1) {
    stage_half(Wb + 64, lds + 32768 + 16384, 0, ldw, sr, pc, wave);
    stage_half(Wb + 64, lds + 32768 + 16384, 1, ldw, sr, pc, wave);
    asm volatile("s_waitcnt vmcnt(4)" ::: "memory");
  } else {
    asm volatile("s_waitcnt vmcnt(0)" ::: "memory");
  }
  __builtin_amdgcn_s_barrier();

  f32x4 acc[8][4] = {};
  const int cxa = r16 & 7;
  const int c0  = (q ^ cxa) * 8;          // elems, ks=0 chunk
  const int c1  = ((4 + q) ^ cxa) * 8;    // elems, ks=1 chunk

  for (int t = 0; t < T; ++t) {
    uint16_t* As  = lds + (t & 1) * 32768;
    uint16_t* Bs  = As + 16384;
    uint16_t* Asn = lds + ((t & 1) ^ 1) * 32768;

    const uint16_t* a_rd = As + (wm * 128 + r16) * 64;
    const uint16_t* b_rd = Bs + (wn * 64  + r16) * 64;

    bf16x8 bfr[4][2];

#pragma unroll
    for (int p = 0; p < 4; ++p) {
      // ---- ds-read this phase's A sub-tile (mi pair {2p, 2p+1}) ----
      bf16x8 af[2][2];
#pragma unroll
      for (int mi2 = 0; mi2 < 2; ++mi2) {
        af[mi2][0] = *(const bf16x8*)(a_rd + (p * 2 + mi2) * 1024 + c0);
        af[mi2][1] = *(const bf16x8*)(a_rd + (p * 2 + mi2) * 1024 + c1);
      }
      if (p == 0) {
        // all B fragments for this K-tile (held in regs across phases)
#pragma unroll
        for (int ni = 0; ni < 4; ++ni) {
          bfr[ni][0] = *(const bf16x8*)(b_rd + ni * 1024 + c0);
          bfr[ni][1] = *(const bf16x8*)(b_rd + ni * 1024 + c1);
        }
        // prefetch A(t+1) into the other buffer (region idle since t-1.p3)
        if (t + 1 < T) {
          stage_half(Ab + (size_t)(t + 1) * 64, Asn, 0, lda, sr, pc, wave);
          stage_half(Ab + (size_t)(t + 1) * 64, Asn, 1, lda, sr, pc, wave);
        }
      } else if (p == 1) {
        // B of this buffer fully consumed in phase 0 -> safe to overwrite
        if (t + 2 < T)
          stage_half(Wb + (size_t)(t + 2) * 64, Bs, 0, ldw, sr, pc, wave);
      } else if (p == 2) {
        if (t + 2 < T)
          stage_half(Wb + (size_t)(t + 2) * 64, Bs, 1, ldw, sr, pc, wave);
      }

      __builtin_amdgcn_s_barrier();
      __builtin_amdgcn_s_setprio(1);
#pragma unroll
      for (int ks = 0; ks < 2; ++ks)
#pragma unroll
        for (int mi2 = 0; mi2 < 2; ++mi2)
#pragma unroll
          for (int ni = 0; ni < 4; ++ni)
            acc[p * 2 + mi2][ni] = __builtin_amdgcn_mfma_f32_16x16x32_bf16(
                af[mi2][ks], bfr[ni][ks], acc[p * 2 + mi2][ni], 0, 0, 0);
      __builtin_amdgcn_s_setprio(0);
      if (p == 3) {
        // boundary: tile t+1 fully resident; only t+2's B (4 loads) in flight
        if (t + 2 < T)      asm volatile("s_waitcnt vmcnt(4)" ::: "memory");
        else if (t + 1 < T) asm volatile("s_waitcnt vmcnt(0)" ::: "memory");
      }
      __builtin_amdgcn_s_barrier();
    }
  }

  // ---- epilogue. C/D layout: col = lane&15, row = (lane>>4)*4 + reg. ----
  TC* Cq = C0;
  int cb = bn;
  if constexpr (SPLIT) {
    if (bn >= 1024) { Cq = C1; cb = bn - 1024; }
  }
  float bv[4];
#pragma unroll
  for (int ni = 0; ni < 4; ++ni) bv[ni] = bias[bn + wn * 64 + ni * 16 + r16];

  float rsum = 0.f;
#pragma unroll
  for (int mi = 0; mi < 8; ++mi) {
    const int rbase = bm + wm * 128 + mi * 16 + q * 4;
#pragma unroll
    for (int r = 0; r < 4; ++r) {
      const size_t rowoff = (size_t)(rbase + r) * ldc + cb;
#pragma unroll
      for (int ni = 0; ni < 4; ++ni) {
        const int loc = wn * 64 + ni * 16 + r16;
        const float v = acc[mi][ni][r] + bv[ni];
        if constexpr (sizeof(TC) == 2)
          Cq[rowoff + loc] = f2b(v);
        else
          Cq[rowoff + loc] = v;
        if constexpr (RECON) {
          const float dd = v - Xref[rowoff + loc];
          rsum += dd * dd;
        }
      }
    }
  }
  if constexpr (RECON) {
#pragma unroll
    for (int m = 1; m < 64; m <<= 1) rsum += __shfl_xor(rsum, m);
    __shared__ float redR[8];
    if (lane == 0) redR[wave] = rsum;
    __syncthreads();
    if (tid == 0) {
      float s = 0.f;
#pragma unroll
      for (int w2 = 0; w2 < 8; ++w2) s += redR[w2];
      atomicAdd(&g_part[256 + (w & 255)], s);
    }
  }
}

// ---------------------------------------------------------------------------
// Fused concept transform: z_t = ReLU(LN(zc@cw1^T + cb1)) @ cw2^T + cb2.
// Block = (concept c, 128-token tile), in-place on z ([NTOK,1024] bf16).
// ---------------------------------------------------------------------------
__global__ __launch_bounds__(256) void concept_fused_kernel(
    uint16_t* __restrict__ z, const uint16_t* __restrict__ c1b,
    const uint16_t* __restrict__ c2b, const float* __restrict__ cb1,
    const float* __restrict__ cg, const float* __restrict__ cbt,
    const float* __restrict__ cb2)
{
  __shared__ __align__(16) uint16_t Az[128 * 64];   // zc tile, then t tile
  __shared__ __align__(16) uint16_t W1s[64 * 64];
  __shared__ __align__(16) uint16_t W2s[64 * 64];

  const int tid  = threadIdx.x;
  const int wave = tid >> 6;
  const int lane = tid & 63;
  const int q    = lane >> 4;
  const int r16  = lane & 15;
  const int c    = blockIdx.y;
  const int m0   = blockIdx.x * 128;

  const int lr = tid >> 3;
  const int pc = tid & 7;

#pragma unroll
  for (int i = 0; i < 4; ++i) {
    const int r = i * 32 + lr;
    const int gc = pc ^ (r & 7);
    gload_lds16(z + (size_t)(m0 + r) * DIM + c * 64 + gc * 8,
                (uint16_t*)((char*)Az + i * 4096 + wave * 1024));
  }
#pragma unroll
  for (int i = 0; i < 2; ++i) {
    const int r = i * 32 + lr;
    const int gc = pc ^ (r & 7);
    gload_lds16(c1b + (size_t)c * 4096 + r * 64 + gc * 8,
                (uint16_t*)((char*)W1s + i * 4096 + wave * 1024));
    gload_lds16(c2b + (size_t)c * 4096 + r * 64 + gc * 8,
                (uint16_t*)((char*)W2s + i * 4096 + wave * 1024));
  }
  __syncthreads();

  // MFMA1: t = zc @ cw1^T
  f32x4 acc[2][4] = {};
#pragma unroll
  for (int ks = 0; ks < 2; ++ks) {
    bf16x8 af[2], wf[4];
#pragma unroll
    for (int mi = 0; mi < 2; ++mi) {
      const int row = wave * 32 + mi * 16 + r16;
      af[mi] = *(const bf16x8*)(Az + row * 64 + ((ks * 4 + q) ^ (row & 7)) * 8);
    }
#pragma unroll
    for (int ni = 0; ni < 4; ++ni) {
      const int d = ni * 16 + r16;
      wf[ni] = *(const bf16x8*)(W1s + d * 64 + ((ks * 4 + q) ^ (d & 7)) * 8);
    }
#pragma unroll
    for (int mi = 0; mi < 2; ++mi)
#pragma unroll
      for (int ni = 0; ni < 4; ++ni)
        acc[mi][ni] = __builtin_amdgcn_mfma_f32_16x16x32_bf16(
            af[mi], wf[ni], acc[mi][ni], 0, 0, 0);
  }

  float b1v[4], cgv[4], cbv[4], b2v[4];
#pragma unroll
  for (int ni = 0; ni < 4; ++ni) {
    const int cn = ni * 16 + r16;
    b1v[ni] = cb1[c * 64 + cn];
    cgv[ni] = cg[c * 64 + cn];
    cbv[ni] = cbt[c * 64 + cn];
    b2v[ni] = cb2[c * 64 + cn];
  }
#pragma unroll
  for (int mi = 0; mi < 2; ++mi) {
#pragma unroll
    for (int r = 0; r < 4; ++r) {
      float s1 = 0.f, s2 = 0.f;
#pragma unroll
      for (int ni = 0; ni < 4; ++ni) {
        const float v = acc[mi][ni][r] + b1v[ni];
        acc[mi][ni][r] = v;
        s1 += v; s2 += v * v;
      }
#pragma unroll
      for (int m = 1; m < 16; m <<= 1) {
        s1 += __shfl_xor(s1, m);
        s2 += __shfl_xor(s2, m);
      }
      const float mean = s1 * (1.f / 64.f);
      const float var  = s2 * (1.f / 64.f) - mean * mean;
      const float rs   = rsqrtf(var + 1e-5f);
      const int row = wave * 32 + mi * 16 + q * 4 + r;
#pragma unroll
      for (int ni = 0; ni < 4; ++ni) {
        const float y = fmaxf((acc[mi][ni][r] - mean) * rs * cgv[ni] + cbv[ni], 0.f);
        const int cn = ni * 16 + r16;
        Az[row * 64 + (((cn >> 3) ^ (row & 7)) * 8) + (cn & 7)] = f2b(y);
      }
    }
  }
  __syncthreads();

  // MFMA2: zt = t @ cw2^T
  f32x4 acc2[2][4] = {};
#pragma unroll
  for (int ks = 0; ks < 2; ++ks) {
    bf16x8 af[2], wf[4];
#pragma unroll
    for (int mi = 0; mi < 2; ++mi) {
      const int row = wave * 32 + mi * 16 + r16;
      af[mi] = *(const bf16x8*)(Az + row * 64 + ((ks * 4 + q) ^ (row & 7)) * 8);
    }
#pragma unroll
    for (int ni = 0; ni < 4; ++ni) {
      const int d = ni * 16 + r16;
      wf[ni] = *(const bf16x8*)(W2s + d * 64 + ((ks * 4 + q) ^ (d & 7)) * 8);
    }
#pragma unroll
    for (int mi = 0; mi < 2; ++mi)
#pragma unroll
      for (int ni = 0; ni < 4; ++ni)
        acc2[mi][ni] = __builtin_amdgcn_mfma_f32_16x16x32_bf16(
            af[mi], wf[ni], acc2[mi][ni], 0, 0, 0);
  }

#pragma unroll
  for (int mi = 0; mi < 2; ++mi)
#pragma unroll
    for (int ni = 0; ni < 4; ++ni) {
      const int cn = ni * 16 + r16;
#pragma unroll
      for (int r = 0; r < 4; ++r) {
        const int row = wave * 32 + mi * 16 + q * 4 + r;
        z[(size_t)(m0 + row) * DIM + c * 64 + cn] = f2b(acc2[mi][ni][r] + b2v[ni]);
      }
    }
}

// ---------------------------------------------------------------------------
// Fused: encoder LN (stats over 2048-wide [mu|lv]) + KL partials + causal.
// Block = 2 tokens, 128 threads/token, u16x8 16B loads (G13).
// ---------------------------------------------------------------------------
__global__ __launch_bounds__(256) void kl_causal_kernel(
    const uint16_t* __restrict__ lv, uint16_t* __restrict__ mu,
    const float* __restrict__ g, const float* __restrict__ b,
    const float* __restrict__ dag_w)
{
  __shared__ __align__(16) float zsh[2][1024];
  __shared__ float dg[256];
  __shared__ float red[2][2][2];   // [token][wave-in-token][stat]
  __shared__ float redk[2][2];     // kl partials
  const int tid  = threadIdx.x;
  const int tk   = tid >> 7;            // token within block
  const int ttid = tid & 127;
  const int wv   = ttid >> 6;           // wave within token
  const int lane = tid & 63;
  const int tok  = blockIdx.x * 2 + tk;
  const int e0   = ttid * 8;            // elem base in [0,1024)

  dg[tid] = ((tid & 15) < (tid >> 4)) ? log1pf(expf(dag_w[tid])) : 0.f;

  const uint16_t* lvp = lv + (size_t)tok * 1024;
  uint16_t*       mup = mu + (size_t)tok * 1024;

  const u16x8 m8 = *(const u16x8*)(mup + e0);
  const u16x8 l8 = *(const u16x8*)(lvp + e0);
  float xm[8], xl[8];
  float s1 = 0.f, s2 = 0.f;
#pragma unroll
  for (int k = 0; k < 8; ++k) {
    xm[k] = b2f(m8[k]);
    xl[k] = b2f(l8[k]);
    s1 += xm[k] + xl[k];
    s2 += xm[k] * xm[k] + xl[k] * xl[k];
  }
#pragma unroll
  for (int m = 1; m < 64; m <<= 1) {
    s1 += __shfl_xor(s1, m);
    s2 += __shfl_xor(s2, m);
  }
  if (lane == 0) { red[tk][wv][0] = s1; red[tk][wv][1] = s2; }
  __syncthreads();
  s1 = red[tk][0][0] + red[tk][1][0];
  s2 = red[tk][0][1] + red[tk][1][1];
  const float mean = s1 * (1.f / 2048.f);
  const float var  = s2 * (1.f / 2048.f) - mean * mean;
  const float rs   = rsqrtf(var + 1e-5f);

  const f32x4 gm0 = *(const f32x4*)(g + e0);
  const f32x4 gm1 = *(const f32x4*)(g + e0 + 4);
  const f32x4 bm0 = *(const f32x4*)(b + e0);
  const f32x4 bm1 = *(const f32x4*)(b + e0 + 4);
  const f32x4 gl0 = *(const f32x4*)(g + 1024 + e0);
  const f32x4 gl1 = *(const f32x4*)(g + 1024 + e0 + 4);
  const f32x4 bl0 = *(const f32x4*)(b + 1024 + e0);
  const f32x4 bl1 = *(const f32x4*)(b + 1024 + e0 + 4);
  float kl = 0.f;
#pragma unroll
  for (int k = 0; k < 8; ++k) {
    const float gk = (k < 4) ? gm0[k] : gm1[k - 4];
    const float bk = (k < 4) ? bm0[k] : bm1[k - 4];
    const float glk = (k < 4) ? gl0[k] : gl1[k - 4];
    const float blk = (k < 4) ? bl0[k] : bl1[k - 4];
    const float zk = (xm[k] - mean) * rs * gk + bk;
    const float y  = (xl[k] - mean) * rs * glk + blk;
    kl += 1.f + y - zk * zk - expf(y);
    zsh[tk][e0 + k] = zk;
  }
#pragma unroll
  for (int m = 1; m < 64; m <<= 1) kl += __shfl_xor(kl, m);
  if (lane == 0) redk[tk][wv] = kl;
  __syncthreads();   // covers zsh, dg, redk
  if (ttid == 0)
    atomicAdd(&g_part[tok & 255], redk[tk][0] + redk[tk][1]);

  // causal: elems [e0, e0+8) all in concept i = e0>>6 (64%8==0)
  const int i  = e0 >> 6;
  const int d0 = e0 & 63;
  f32x4 sa = *(const f32x4*)&zsh[tk][e0];
  f32x4 sb = *(const f32x4*)&zsh[tk][e0 + 4];
  for (int j = 0; j < i; ++j) {
    const float w = dg[i * 16 + j];
    const f32x4 za = *(const f32x4*)&zsh[tk][j * 64 + d0];
    const f32x4 zb = *(const f32x4*)&zsh[tk][j * 64 + d0 + 4];
#pragma unroll
    for (int k = 0; k < 4; ++k) { sa[k] += w * za[k]; sb[k] += w * zb[k]; }
  }
  u16x8 o;
#pragma unroll
  for (int k = 0; k < 4; ++k) { o[k] = f2b(sa[k]); o[4 + k] = f2b(sb[k]); }
  *(u16x8*)(mup + e0) = o;
}

// ---------------------------------------------------------------------------
// LayerNorm(1024) + ReLU, in-place. Block = 2 rows, 128 thr/row, u16x8 I/O.
// ---------------------------------------------------------------------------
__global__ __launch_bounds__(256) void ln_relu_kernel(
    uint16_t* __restrict__ data, const float* __restrict__ g,
    const float* __restrict__ b)
{
  __shared__ float red[2][2][2];
  const int tid  = threadIdx.x;
  const int tk   = tid >> 7;
  const int ttid = tid & 127;
  const int wv   = ttid >> 6;
  const int lane = tid & 63;
  const int e0   = ttid * 8;
  uint16_t* p = data + (size_t)(blockIdx.x * 2 + tk) * 1024;

  const u16x8 v8 = *(const u16x8*)(p + e0);
  float x[8];
  float s1 = 0.f, s2 = 0.f;
#pragma unroll
  for (int k = 0; k < 8; ++k) {
    x[k] = b2f(v8[k]);
    s1 += x[k];
    s2 += x[k] * x[k];
  }
#pragma unroll
  for (int m = 1; m < 64; m <<= 1) {
    s1 += __shfl_xor(s1, m);
    s2 += __shfl_xor(s2, m);
  }
  if (lane == 0) { red[tk][wv][0] = s1; red[tk][wv][1] = s2; }
  __syncthreads();
  s1 = red[tk][0][0] + red[tk][1][0];
  s2 = red[tk][0][1] + red[tk][1][1];
  const float mean = s1 * (1.f / 1024.f);
  const float var  = s2 * (1.f / 1024.f) - mean * mean;
  const float rs   = rsqrtf(var + 1e-5f);

  const f32x4 g0 = *(const f32x4*)(g + e0);
  const f32x4 g1 = *(const f32x4*)(g + e0 + 4);
  const f32x4 b0 = *(const f32x4*)(b + e0);
  const f32x4 b1 = *(const f32x4*)(b + e0 + 4);
  u16x8 o;
#pragma unroll
  for (int k = 0; k < 8; ++k) {
    const float gk = (k < 4) ? g0[k] : g1[k - 4];
    const float bk = (k < 4) ? b0[k] : b1[k - 4];
    o[k] = f2b(fmaxf((x[k] - mean) * rs * gk + bk, 0.f));
  }
  *(u16x8*)(p + e0) = o;
}

// ---------------------------------------------------------------------------
// finalize: sum the 256+256 partial slots, emit the 4 loss scalars.
// ---------------------------------------------------------------------------
__global__ __launch_bounds__(256) void finalize_kernel(float* __restrict__ out_tail)
{
  const int tid = threadIdx.x;
  float kl = g_part[tid];
  float rc = g_part[256 + tid];
#pragma unroll
  for (int m = 1; m < 64; m <<= 1) {
    kl += __shfl_xor(kl, m);
    rc += __shfl_xor(rc, m);
  }
  __shared__ float red[8];
  const int wave = tid >> 6, lane = tid & 63;
  if (lane == 0) { red[wave] = kl; red[4 + wave] = rc; }
  __syncthreads();
  if (tid == 0) {
    const float kls = red[0] + red[1] + red[2] + red[3];
    const float rcs = red[4] + red[5] + red[6] + red[7];
    const float kl_l   = -0.5f * kls * (1.f / (16384.f * 1024.f));
    const float recon  = rcs * (1.f / 16777216.f);
    const float dagl   = g_scal[2];
    out_tail[0] = recon + 0.3f * kl_l + 1.0f * dagl;
    out_tail[1] = kl_l;
    out_tail[2] = recon;
    out_tail[3] = dagl;
  }
}

// ---------------------------------------------------------------------------
extern "C" void kernel_launch(void* const* d_in, const int* in_sizes, int n_in,
                              void* d_out, int out_size, void* d_ws, size_t ws_size,
                              hipStream_t stream) {
  const float* x      = (const float*)d_in[0];
  const float* enc_w  = (const float*)d_in[1];
  const float* enc_b  = (const float*)d_in[2];
  const float* enc_g  = (const float*)d_in[3];
  const float* enc_bt = (const float*)d_in[4];
  const float* dag_w  = (const float*)d_in[5];
  const float* cw1    = (const float*)d_in[6];
  const float* cb1    = (const float*)d_in[7];
  const float* cg     = (const float*)d_in[8];
  const float* cbt    = (const float*)d_in[9];
  const float* cw2    = (const float*)d_in[10];
  const float* cb2    = (const float*)d_in[11];
  const float* dec_w1 = (const float*)d_in[12];
  const float* dec_b1 = (const float*)d_in[13];
  const float* dec_g  = (const float*)d_in[14];
  const float* dec_bt = (const float*)d_in[15];
  const float* dec_w2 = (const float*)d_in[16];
  const float* dec_b2 = (const float*)d_in[17];

  uint16_t* S    = (uint16_t*)d_ws;                       // [16384x1024] bf16, 32 MiB
  uint16_t* Wbf  = (uint16_t*)((char*)d_ws + (size_t)NTOK * DIM * 2);
  uint16_t* ewb  = Wbf;                                   // enc_w   2,097,152
  uint16_t* d1b  = Wbf + 2097152;                         // dec_w1  1,048,576
  uint16_t* d2b  = Wbf + 3145728;                         // dec_w2  1,048,576
  uint16_t* c1b  = Wbf + 4194304;                         // cw1       65,536
  uint16_t* c2b  = Wbf + 4259840;                         // cw2       65,536

  uint16_t* Obf  = (uint16_t*)d_out;                      // bf16 scratch (lower half)
  uint16_t* xbf  = Obf + (size_t)NOUT_ELEMS;              // x_bf16 (upper half)
  float*    O    = (float*)d_out;                         // final fp32 x_recon + losses

  // 1. weights -> bf16 (+ dag/partials init in block 2112)
  cvt_weights_kernel<<<2113, 256, 0, stream>>>(
      enc_w, dec_w1, dec_w2, cw1, cw2, Wbf, dag_w);

  // 1b. x -> bf16
  cvt_x_kernel<<<NOUT_ELEMS / 8 / 256, 256, 0, stream>>>(x, xbf);

  // 2. encoder GEMM (merged, N=2048, split epilogue): mu -> Obf, lv -> S
  gemm256_kernel<uint16_t, true, false>
      <<<dim3(64, 8, 1), 512, 0, stream>>>(
      xbf, ewb, enc_b, Obf, S, nullptr, DIM, DIM, DIM, DIM);

  // 3. fused LN + KL + causal: z_causal overwrites mu in Obf (xbf now dead)
  kl_causal_kernel<<<NTOK / 2, 256, 0, stream>>>(S, Obf, enc_g, enc_bt, dag_w);

  // 4. fused concept transform (concept1 + LN64 + ReLU + concept2), in-place
  concept_fused_kernel<<<dim3(128, 16, 1), 256, 0, stream>>>(
      Obf, c1b, c2b, cb1, cg, cbt, cb2);

  // 5. decoder GEMM1: d_pre = z_t @ dec_w1^T + dec_b1 -> S
  gemm256_kernel<uint16_t, false, false>
      <<<dim3(64, 4, 1), 512, 0, stream>>>(
      Obf, d1b, dec_b1, S, S, nullptr, DIM, DIM, DIM, DIM);

  // 6. decoder LN + ReLU (in-place on S)
  ln_relu_kernel<<<NTOK / 2, 256, 0, stream>>>(S, dec_g, dec_bt);

  // 7. decoder GEMM2 + fused recon: x_recon = d @ dec_w2^T + dec_b2 -> O (fp32)
  gemm256_kernel<float, false, true>
      <<<dim3(64, 4, 1), 512, 0, stream>>>(
      S, d2b, dec_b2, O, O, x, DIM, DIM, DIM, DIM);

  // 8. final scalars
  finalize_kernel<<<1, 256, 0, stream>>>(O + (size_t)NOUT_ELEMS);
}

// Round 6
// 367.724 us; speedup vs baseline: 1.0493x; 1.0088x over previous
//
#include <hip/hip_runtime.h>
#include <stdint.h>

// ---------------------------------------------------------------------------
// CausalVAELayer forward, MI355X (gfx950). FP32 in / FP32 out.
// Internally: bf16 MFMA GEMMs, fp32 acc, bf16 intermediates.
// B=8,S=2048,D=1024,C=16,CD=64,L=1024. Tokens N=16384.
//
// ROUND 15 (base = round-14, best 371.0 us; GEMM K-loop untouched):
// (a) cvt_x + cvt_weights + dag_init merged into ONE launch (cvt_all).
// (b) If ws_size >= 72.3 MiB: x_bf16 lives in the WORKSPACE (xbf2) --
//     encoder reads A from there, and decoder GEMM2's RECON compares
//     against bf16 xbf2 instead of fp32 x (FETCH 98 -> 34 MB on GEMM2).
//     No race: ws is never written by GEMM2 (unlike d_out's upper half).
//     If ws too small: exact round-14 behavior (fp32 Xref fallback).
// ---------------------------------------------------------------------------

#define NTOK   16384
#define DIM    1024
#define NC     16
#define CD     64
#define NOUT_ELEMS 16777216  // NTOK*DIM

typedef float f32x4 __attribute__((ext_vector_type(4)));
typedef __bf16 bf16x8 __attribute__((ext_vector_type(8)));
typedef unsigned short u16x4 __attribute__((ext_vector_type(4)));
typedef unsigned short u16x8 __attribute__((ext_vector_type(8)));

__device__ float g_scal[3];    // [2]=dag_loss
__device__ float g_part[512];  // [0..256)=kl partials, [256..512)=recon partials

__device__ __forceinline__ float b2f(uint16_t u) {
  union { uint32_t i; float f; } v; v.i = ((uint32_t)u) << 16; return v.f;
}
__device__ __forceinline__ uint16_t f2b(float f) {
  union { float f; uint32_t i; } v; v.f = f;
  uint32_t x = v.i;
  return (uint16_t)((x + 0x7fffu + ((x >> 16) & 1u)) >> 16);  // RNE
}

__device__ __forceinline__ void gload_lds16(const uint16_t* g, uint16_t* l) {
  __builtin_amdgcn_global_load_lds(
      (const __attribute__((address_space(1))) void*)g,
      (__attribute__((address_space(3))) void*)l, 16, 0, 0);
}

// convert 8 fp32 -> 8 bf16 (RNE), 16B store
__device__ __forceinline__ void cvt8(const float* s, uint16_t* d) {
  const f32x4 a = *(const f32x4*)s;
  const f32x4 b = *(const f32x4*)(s + 4);
  u16x8 o;
  o[0]=f2b(a[0]); o[1]=f2b(a[1]); o[2]=f2b(a[2]); o[3]=f2b(a[3]);
  o[4]=f2b(b[0]); o[5]=f2b(b[1]); o[6]=f2b(b[2]); o[7]=f2b(b[3]);
  *(u16x8*)d = o;
}

// ---------------------------------------------------------------------------
// One launch: blocks [0,8192) convert x -> xdst; [8192,10304) convert the 5
// weight tensors -> Wbf; block 10304 zeroes partials + computes dag_loss.
// ---------------------------------------------------------------------------
__global__ __launch_bounds__(256) void cvt_all_kernel(
    const float* __restrict__ x, uint16_t* __restrict__ xdst,
    const float* __restrict__ ew, const float* __restrict__ d1,
    const float* __restrict__ d2, const float* __restrict__ c1,
    const float* __restrict__ c2, uint16_t* __restrict__ out,
    const float* __restrict__ dag_w)
{
  const int blk = blockIdx.x;
  if (blk < 8192) {
    const int i = blk * 256 + threadIdx.x;
    cvt8(x + (size_t)i * 8, xdst + (size_t)i * 8);
    return;
  }
  if (blk == 10304) {
    const int t = threadIdx.x;
    g_part[t] = 0.f;
    g_part[256 + t] = 0.f;
    const int i2 = t >> 4, j2 = t & 15;
    const float v = (j2 < i2) ? log1pf(expf(dag_w[t])) : 0.f;
    float s = v;
#pragma unroll
    for (int m = 1; m < 64; m <<= 1) s += __shfl_xor(s, m);
    __shared__ float red[4];
    const int wave = t >> 6, lane = t & 63;
    if (lane == 0) red[wave] = s;
    __syncthreads();
    if (t == 0)
      g_scal[2] = red[0] + red[1] + red[2] + red[3] + 16.f;  // trace(expm)=C
    return;
  }
  const int i = (blk - 8192) * 256 + threadIdx.x;  // elem8 idx, total 540672
  const float* src; uint16_t* dst; int off;
  if (i < 262144)      { src = ew; dst = out;           off = i; }
  else if (i < 393216) { src = d1; dst = out + 2097152; off = i - 262144; }
  else if (i < 524288) { src = d2; dst = out + 3145728; off = i - 393216; }
  else if (i < 532480) { src = c1; dst = out + 4194304; off = i - 524288; }
  else                 { src = c2; dst = out + 4259840; off = i - 532480; }
  cvt8(src + (size_t)off * 8, dst + (size_t)off * 8);
}

// ---------------------------------------------------------------------------
// Stage one 128-row half of a [256 x 64] bf16 K-tile panel into an LDS region
// (32 KB, rows of 128 B, 16B-chunk XOR swizzle: logical chunk c of row r at
// physical slot c ^ (r&7)). 2 global_load_lds (width 16) per wave.
// 512 threads: sr = tid>>3 in [0,64), pc = tid&7.
// ---------------------------------------------------------------------------
__device__ __forceinline__ void stage_half(
    const uint16_t* __restrict__ G, uint16_t* L, int h, int lda,
    int sr, int pc, int wave)
{
#pragma unroll
  for (int i = 0; i < 2; ++i) {
    const int r = h * 128 + i * 64 + sr;
    gload_lds16(G + (size_t)r * lda + (size_t)((pc ^ (sr & 7)) * 8),
                (uint16_t*)((char*)L + h * 16384 + i * 8192 + wave * 1024));
  }
}

// ---------------------------------------------------------------------------
// 256x256-tile pipelined GEMM (round-11/14 verified): 4 phases, vmcnt(4),
// XCD-chunked bn-fastest swizzle, ni-innermost epilogue.
// RECON_MODE: 0 = none, 1 = compare vs fp32 Xref, 2 = compare vs bf16 Xref.
// ---------------------------------------------------------------------------
template<typename TC, bool SPLIT, int RECON_MODE>
__global__ __launch_bounds__(512, 2) void gemm256_kernel(
    const uint16_t* __restrict__ A, const uint16_t* __restrict__ Wm,
    const float* __restrict__ bias, TC* __restrict__ C0, TC* __restrict__ C1,
    const void* __restrict__ Xref,
    int K, int lda, int ldw, int ldc)
{
  __shared__ __align__(16) uint16_t lds[65536];  // 128 KiB

  const int tid  = threadIdx.x;
  const int wave = tid >> 6;
  const int lane = tid & 63;
  const int q    = lane >> 4;
  const int r16  = lane & 15;
  const int wm   = wave >> 2;   // 0..1
  const int wn   = wave & 3;    // 0..3
  const int sr   = tid >> 3;    // 0..63
  const int pc   = tid & 7;

  const int gx  = gridDim.x;
  const int gy  = gridDim.y;
  const int nwg = gx * gy;
  const int o   = blockIdx.y * gx + blockIdx.x;
  const int w   = (o & 7) * (nwg >> 3) + (o >> 3);
  const int bn  = (w & (gy - 1)) * 256;
  const int bm  = (w >> __builtin_ctz(gy)) * 256;

  const uint16_t* Ab = A  + (size_t)bm * lda;
  const uint16_t* Wb = Wm + (size_t)bn * ldw;

  const int T = K >> 6;  // K-tiles of 64

  // ---- prologue: tile0 A+B -> buf0; tile1 B -> buf1 ----
  stage_half(Ab,      lds,                 0, lda, sr, pc, wave);
  stage_half(Ab,      lds,                 1, lda, sr, pc, wave);
  stage_half(Wb,      lds + 16384,         0, ldw, sr, pc, wave);
  stage_half(Wb,      lds + 16384,         1, ldw, sr, pc, wave);
  if (T > 1) {
    stage_half(Wb + 64, lds + 32768 + 16384, 0, ldw, sr, pc, wave);
    stage_half(Wb + 64, lds + 32768 + 16384, 1, ldw, sr, pc, wave);
    asm volatile("s_waitcnt vmcnt(4)" ::: "memory");
  } else {
    asm volatile("s_waitcnt vmcnt(0)" ::: "memory");
  }
  __builtin_amdgcn_s_barrier();

  f32x4 acc[8][4] = {};
  const int cxa = r16 & 7;
  const int c0  = (q ^ cxa) * 8;          // elems, ks=0 chunk
  const int c1  = ((4 + q) ^ cxa) * 8;    // elems, ks=1 chunk

  for (int t = 0; t < T; ++t) {
    uint16_t* As  = lds + (t & 1) * 32768;
    uint16_t* Bs  = As + 16384;
    uint16_t* Asn = lds + ((t & 1) ^ 1) * 32768;

    const uint16_t* a_rd = As + (wm * 128 + r16) * 64;
    const uint16_t* b_rd = Bs + (wn * 64  + r16) * 64;

    bf16x8 bfr[4][2];

#pragma unroll
    for (int p = 0; p < 4; ++p) {
      // ---- ds-read this phase's A sub-tile (mi pair {2p, 2p+1}) ----
      bf16x8 af[2][2];
#pragma unroll
      for (int mi2 = 0; mi2 < 2; ++mi2) {
        af[mi2][0] = *(const bf16x8*)(a_rd + (p * 2 + mi2) * 1024 + c0);
        af[mi2][1] = *(const bf16x8*)(a_rd + (p * 2 + mi2) * 1024 + c1);
      }
      if (p == 0) {
        // all B fragments for this K-tile (held in regs across phases)
#pragma unroll
        for (int ni = 0; ni < 4; ++ni) {
          bfr[ni][0] = *(const bf16x8*)(b_rd + ni * 1024 + c0);
          bfr[ni][1] = *(const bf16x8*)(b_rd + ni * 1024 + c1);
        }
        // prefetch A(t+1) into the other buffer (region idle since t-1.p3)
        if (t + 1 < T) {
          stage_half(Ab + (size_t)(t + 1) * 64, Asn, 0, lda, sr, pc, wave);
          stage_half(Ab + (size_t)(t + 1) * 64, Asn, 1, lda, sr, pc, wave);
        }
      } else if (p == 1) {
        // B of this buffer fully consumed in phase 0 -> safe to overwrite
        if (t + 2 < T)
          stage_half(Wb + (size_t)(t + 2) * 64, Bs, 0, ldw, sr, pc, wave);
      } else if (p == 2) {
        if (t + 2 < T)
          stage_half(Wb + (size_t)(t + 2) * 64, Bs, 1, ldw, sr, pc, wave);
      }

      __builtin_amdgcn_s_barrier();
      __builtin_amdgcn_s_setprio(1);
#pragma unroll
      for (int ks = 0; ks < 2; ++ks)
#pragma unroll
        for (int mi2 = 0; mi2 < 2; ++mi2)
#pragma unroll
          for (int ni = 0; ni < 4; ++ni)
            acc[p * 2 + mi2][ni] = __builtin_amdgcn_mfma_f32_16x16x32_bf16(
                af[mi2][ks], bfr[ni][ks], acc[p * 2 + mi2][ni], 0, 0, 0);
      __builtin_amdgcn_s_setprio(0);
      if (p == 3) {
        // boundary: tile t+1 fully resident; only t+2's B (4 loads) in flight
        if (t + 2 < T)      asm volatile("s_waitcnt vmcnt(4)" ::: "memory");
        else if (t + 1 < T) asm volatile("s_waitcnt vmcnt(0)" ::: "memory");
      }
      __builtin_amdgcn_s_barrier();
    }
  }

  // ---- epilogue. C/D layout: col = lane&15, row = (lane>>4)*4 + reg. ----
  TC* Cq = C0;
  int cb = bn;
  if constexpr (SPLIT) {
    if (bn >= 1024) { Cq = C1; cb = bn - 1024; }
  }
  float bv[4];
#pragma unroll
  for (int ni = 0; ni < 4; ++ni) bv[ni] = bias[bn + wn * 64 + ni * 16 + r16];

  float rsum = 0.f;
#pragma unroll
  for (int mi = 0; mi < 8; ++mi) {
    const int rbase = bm + wm * 128 + mi * 16 + q * 4;
#pragma unroll
    for (int r = 0; r < 4; ++r) {
      const size_t rowoff = (size_t)(rbase + r) * ldc + cb;
#pragma unroll
      for (int ni = 0; ni < 4; ++ni) {
        const int loc = wn * 64 + ni * 16 + r16;
        const float v = acc[mi][ni][r] + bv[ni];
        if constexpr (sizeof(TC) == 2)
          Cq[rowoff + loc] = f2b(v);
        else
          Cq[rowoff + loc] = v;
        if constexpr (RECON_MODE == 1) {
          const float dd = v - ((const float*)Xref)[rowoff + loc];
          rsum += dd * dd;
        } else if constexpr (RECON_MODE == 2) {
          const float dd = v - b2f(((const uint16_t*)Xref)[rowoff + loc]);
          rsum += dd * dd;
        }
      }
    }
  }
  if constexpr (RECON_MODE != 0) {
#pragma unroll
    for (int m = 1; m < 64; m <<= 1) rsum += __shfl_xor(rsum, m);
    __shared__ float redR[8];
    if (lane == 0) redR[wave] = rsum;
    __syncthreads();
    if (tid == 0) {
      float s = 0.f;
#pragma unroll
      for (int w2 = 0; w2 < 8; ++w2) s += redR[w2];
      atomicAdd(&g_part[256 + (w & 255)], s);
    }
  }
}

// ---------------------------------------------------------------------------
// Fused concept transform: z_t = ReLU(LN(zc@cw1^T + cb1)) @ cw2^T + cb2.
// Block = (concept c, 128-token tile), in-place on z ([NTOK,1024] bf16).
// ---------------------------------------------------------------------------
__global__ __launch_bounds__(256) void concept_fused_kernel(
    uint16_t* __restrict__ z, const uint16_t* __restrict__ c1b,
    const uint16_t* __restrict__ c2b, const float* __restrict__ cb1,
    const float* __restrict__ cg, const float* __restrict__ cbt,
    const float* __restrict__ cb2)
{
  __shared__ __align__(16) uint16_t Az[128 * 64];   // zc tile, then t tile
  __shared__ __align__(16) uint16_t W1s[64 * 64];
  __shared__ __align__(16) uint16_t W2s[64 * 64];

  const int tid  = threadIdx.x;
  const int wave = tid >> 6;
  const int lane = tid & 63;
  const int q    = lane >> 4;
  const int r16  = lane & 15;
  const int c    = blockIdx.y;
  const int m0   = blockIdx.x * 128;

  const int lr = tid >> 3;
  const int pc = tid & 7;

#pragma unroll
  for (int i = 0; i < 4; ++i) {
    const int r = i * 32 + lr;
    const int gc = pc ^ (r & 7);
    gload_lds16(z + (size_t)(m0 + r) * DIM + c * 64 + gc * 8,
                (uint16_t*)((char*)Az + i * 4096 + wave * 1024));
  }
#pragma unroll
  for (int i = 0; i < 2; ++i) {
    const int r = i * 32 + lr;
    const int gc = pc ^ (r & 7);
    gload_lds16(c1b + (size_t)c * 4096 + r * 64 + gc * 8,
                (uint16_t*)((char*)W1s + i * 4096 + wave * 1024));
    gload_lds16(c2b + (size_t)c * 4096 + r * 64 + gc * 8,
                (uint16_t*)((char*)W2s + i * 4096 + wave * 1024));
  }
  __syncthreads();

  // MFMA1: t = zc @ cw1^T
  f32x4 acc[2][4] = {};
#pragma unroll
  for (int ks = 0; ks < 2; ++ks) {
    bf16x8 af[2], wf[4];
#pragma unroll
    for (int mi = 0; mi < 2; ++mi) {
      const int row = wave * 32 + mi * 16 + r16;
      af[mi] = *(const bf16x8*)(Az + row * 64 + ((ks * 4 + q) ^ (row & 7)) * 8);
    }
#pragma unroll
    for (int ni = 0; ni < 4; ++ni) {
      const int d = ni * 16 + r16;
      wf[ni] = *(const bf16x8*)(W1s + d * 64 + ((ks * 4 + q) ^ (d & 7)) * 8);
    }
#pragma unroll
    for (int mi = 0; mi < 2; ++mi)
#pragma unroll
      for (int ni = 0; ni < 4; ++ni)
        acc[mi][ni] = __builtin_amdgcn_mfma_f32_16x16x32_bf16(
            af[mi], wf[ni], acc[mi][ni], 0, 0, 0);
  }

  float b1v[4], cgv[4], cbv[4], b2v[4];
#pragma unroll
  for (int ni = 0; ni < 4; ++ni) {
    const int cn = ni * 16 + r16;
    b1v[ni] = cb1[c * 64 + cn];
    cgv[ni] = cg[c * 64 + cn];
    cbv[ni] = cbt[c * 64 + cn];
    b2v[ni] = cb2[c * 64 + cn];
  }
#pragma unroll
  for (int mi = 0; mi < 2; ++mi) {
#pragma unroll
    for (int r = 0; r < 4; ++r) {
      float s1 = 0.f, s2 = 0.f;
#pragma unroll
      for (int ni = 0; ni < 4; ++ni) {
        const float v = acc[mi][ni][r] + b1v[ni];
        acc[mi][ni][r] = v;
        s1 += v; s2 += v * v;
      }
#pragma unroll
      for (int m = 1; m < 16; m <<= 1) {
        s1 += __shfl_xor(s1, m);
        s2 += __shfl_xor(s2, m);
      }
      const float mean = s1 * (1.f / 64.f);
      const float var  = s2 * (1.f / 64.f) - mean * mean;
      const float rs   = rsqrtf(var + 1e-5f);
      const int row = wave * 32 + mi * 16 + q * 4 + r;
#pragma unroll
      for (int ni = 0; ni < 4; ++ni) {
        const float y = fmaxf((acc[mi][ni][r] - mean) * rs * cgv[ni] + cbv[ni], 0.f);
        const int cn = ni * 16 + r16;
        Az[row * 64 + (((cn >> 3) ^ (row & 7)) * 8) + (cn & 7)] = f2b(y);
      }
    }
  }
  __syncthreads();

  // MFMA2: zt = t @ cw2^T
  f32x4 acc2[2][4] = {};
#pragma unroll
  for (int ks = 0; ks < 2; ++ks) {
    bf16x8 af[2], wf[4];
#pragma unroll
    for (int mi = 0; mi < 2; ++mi) {
      const int row = wave * 32 + mi * 16 + r16;
      af[mi] = *(const bf16x8*)(Az + row * 64 + ((ks * 4 + q) ^ (row & 7)) * 8);
    }
#pragma unroll
    for (int ni = 0; ni < 4; ++ni) {
      const int d = ni * 16 + r16;
      wf[ni] = *(const bf16x8*)(W2s + d * 64 + ((ks * 4 + q) ^ (d & 7)) * 8);
    }
#pragma unroll
    for (int mi = 0; mi < 2; ++mi)
#pragma unroll
      for (int ni = 0; ni < 4; ++ni)
        acc2[mi][ni] = __builtin_amdgcn_mfma_f32_16x16x32_bf16(
            af[mi], wf[ni], acc2[mi][ni], 0, 0, 0);
  }

#pragma unroll
  for (int mi = 0; mi < 2; ++mi)
#pragma unroll
    for (int ni = 0; ni < 4; ++ni) {
      const int cn = ni * 16 + r16;
#pragma unroll
      for (int r = 0; r < 4; ++r) {
        const int row = wave * 32 + mi * 16 + q * 4 + r;
        z[(size_t)(m0 + row) * DIM + c * 64 + cn] = f2b(acc2[mi][ni][r] + b2v[ni]);
      }
    }
}

// ---------------------------------------------------------------------------
// Fused: encoder LN (stats over 2048-wide [mu|lv]) + KL partials + causal.
// Block = 2 tokens, 128 threads/token, u16x8 16B loads (G13).
// ---------------------------------------------------------------------------
__global__ __launch_bounds__(256) void kl_causal_kernel(
    const uint16_t* __restrict__ lv, uint16_t* __restrict__ mu,
    const float* __restrict__ g, const float* __restrict__ b,
    const float* __restrict__ dag_w)
{
  __shared__ __align__(16) float zsh[2][1024];
  __shared__ float dg[256];
  __shared__ float red[2][2][2];   // [token][wave-in-token][stat]
  __shared__ float redk[2][2];     // kl partials
  const int tid  = threadIdx.x;
  const int tk   = tid >> 7;            // token within block
  const int ttid = tid & 127;
  const int wv   = ttid >> 6;           // wave within token
  const int lane = tid & 63;
  const int tok  = blockIdx.x * 2 + tk;
  const int e0   = ttid * 8;            // elem base in [0,1024)

  dg[tid] = ((tid & 15) < (tid >> 4)) ? log1pf(expf(dag_w[tid])) : 0.f;

  const uint16_t* lvp = lv + (size_t)tok * 1024;
  uint16_t*       mup = mu + (size_t)tok * 1024;

  const u16x8 m8 = *(const u16x8*)(mup + e0);
  const u16x8 l8 = *(const u16x8*)(lvp + e0);
  float xm[8], xl[8];
  float s1 = 0.f, s2 = 0.f;
#pragma unroll
  for (int k = 0; k < 8; ++k) {
    xm[k] = b2f(m8[k]);
    xl[k] = b2f(l8[k]);
    s1 += xm[k] + xl[k];
    s2 += xm[k] * xm[k] + xl[k] * xl[k];
  }
#pragma unroll
  for (int m = 1; m < 64; m <<= 1) {
    s1 += __shfl_xor(s1, m);
    s2 += __shfl_xor(s2, m);
  }
  if (lane == 0) { red[tk][wv][0] = s1; red[tk][wv][1] = s2; }
  __syncthreads();
  s1 = red[tk][0][0] + red[tk][1][0];
  s2 = red[tk][0][1] + red[tk][1][1];
  const float mean = s1 * (1.f / 2048.f);
  const float var  = s2 * (1.f / 2048.f) - mean * mean;
  const float rs   = rsqrtf(var + 1e-5f);

  const f32x4 gm0 = *(const f32x4*)(g + e0);
  const f32x4 gm1 = *(const f32x4*)(g + e0 + 4);
  const f32x4 bm0 = *(const f32x4*)(b + e0);
  const f32x4 bm1 = *(const f32x4*)(b + e0 + 4);
  const f32x4 gl0 = *(const f32x4*)(g + 1024 + e0);
  const f32x4 gl1 = *(const f32x4*)(g + 1024 + e0 + 4);
  const f32x4 bl0 = *(const f32x4*)(b + 1024 + e0);
  const f32x4 bl1 = *(const f32x4*)(b + 1024 + e0 + 4);
  float kl = 0.f;
#pragma unroll
  for (int k = 0; k < 8; ++k) {
    const float gk = (k < 4) ? gm0[k] : gm1[k - 4];
    const float bk = (k < 4) ? bm0[k] : bm1[k - 4];
    const float glk = (k < 4) ? gl0[k] : gl1[k - 4];
    const float blk = (k < 4) ? bl0[k] : bl1[k - 4];
    const float zk = (xm[k] - mean) * rs * gk + bk;
    const float y  = (xl[k] - mean) * rs * glk + blk;
    kl += 1.f + y - zk * zk - expf(y);
    zsh[tk][e0 + k] = zk;
  }
#pragma unroll
  for (int m = 1; m < 64; m <<= 1) kl += __shfl_xor(kl, m);
  if (lane == 0) redk[tk][wv] = kl;
  __syncthreads();   // covers zsh, dg, redk
  if (ttid == 0)
    atomicAdd(&g_part[tok & 255], redk[tk][0] + redk[tk][1]);

  // causal: elems [e0, e0+8) all in concept i = e0>>6 (64%8==0)
  const int i  = e0 >> 6;
  const int d0 = e0 & 63;
  f32x4 sa = *(const f32x4*)&zsh[tk][e0];
  f32x4 sb = *(const f32x4*)&zsh[tk][e0 + 4];
  for (int j = 0; j < i; ++j) {
    const float w = dg[i * 16 + j];
    const f32x4 za = *(const f32x4*)&zsh[tk][j * 64 + d0];
    const f32x4 zb = *(const f32x4*)&zsh[tk][j * 64 + d0 + 4];
#pragma unroll
    for (int k = 0; k < 4; ++k) { sa[k] += w * za[k]; sb[k] += w * zb[k]; }
  }
  u16x8 o;
#pragma unroll
  for (int k = 0; k < 4; ++k) { o[k] = f2b(sa[k]); o[4 + k] = f2b(sb[k]); }
  *(u16x8*)(mup + e0) = o;
}

// ---------------------------------------------------------------------------
// LayerNorm(1024) + ReLU, in-place. Block = 2 rows, 128 thr/row, u16x8 I/O.
// ---------------------------------------------------------------------------
__global__ __launch_bounds__(256) void ln_relu_kernel(
    uint16_t* __restrict__ data, const float* __restrict__ g,
    const float* __restrict__ b)
{
  __shared__ float red[2][2][2];
  const int tid  = threadIdx.x;
  const int tk   = tid >> 7;
  const int ttid = tid & 127;
  const int wv   = ttid >> 6;
  const int lane = tid & 63;
  const int e0   = ttid * 8;
  uint16_t* p = data + (size_t)(blockIdx.x * 2 + tk) * 1024;

  const u16x8 v8 = *(const u16x8*)(p + e0);
  float x[8];
  float s1 = 0.f, s2 = 0.f;
#pragma unroll
  for (int k = 0; k < 8; ++k) {
    x[k] = b2f(v8[k]);
    s1 += x[k];
    s2 += x[k] * x[k];
  }
#pragma unroll
  for (int m = 1; m < 64; m <<= 1) {
    s1 += __shfl_xor(s1, m);
    s2 += __shfl_xor(s2, m);
  }
  if (lane == 0) { red[tk][wv][0] = s1; red[tk][wv][1] = s2; }
  __syncthreads();
  s1 = red[tk][0][0] + red[tk][1][0];
  s2 = red[tk][0][1] + red[tk][1][1];
  const float mean = s1 * (1.f / 1024.f);
  const float var  = s2 * (1.f / 1024.f) - mean * mean;
  const float rs   = rsqrtf(var + 1e-5f);

  const f32x4 g0 = *(const f32x4*)(g + e0);
  const f32x4 g1 = *(const f32x4*)(g + e0 + 4);
  const f32x4 b0 = *(const f32x4*)(b + e0);
  const f32x4 b1 = *(const f32x4*)(b + e0 + 4);
  u16x8 o;
#pragma unroll
  for (int k = 0; k < 8; ++k) {
    const float gk = (k < 4) ? g0[k] : g1[k - 4];
    const float bk = (k < 4) ? b0[k] : b1[k - 4];
    o[k] = f2b(fmaxf((x[k] - mean) * rs * gk + bk, 0.f));
  }
  *(u16x8*)(p + e0) = o;
}

// ---------------------------------------------------------------------------
// finalize: sum the 256+256 partial slots, emit the 4 loss scalars.
// ---------------------------------------------------------------------------
__global__ __launch_bounds__(256) void finalize_kernel(float* __restrict__ out_tail)
{
  const int tid = threadIdx.x;
  float kl = g_part[tid];
  float rc = g_part[256 + tid];
#pragma unroll
  for (int m = 1; m < 64; m <<= 1) {
    kl += __shfl_xor(kl, m);
    rc += __shfl_xor(rc, m);
  }
  __shared__ float red[8];
  const int wave = tid >> 6, lane = tid & 63;
  if (lane == 0) { red[wave] = kl; red[4 + wave] = rc; }
  __syncthreads();
  if (tid == 0) {
    const float kls = red[0] + red[1] + red[2] + red[3];
    const float rcs = red[4] + red[5] + red[6] + red[7];
    const float kl_l   = -0.5f * kls * (1.f / (16384.f * 1024.f));
    const float recon  = rcs * (1.f / 16777216.f);
    const float dagl   = g_scal[2];
    out_tail[0] = recon + 0.3f * kl_l + 1.0f * dagl;
    out_tail[1] = kl_l;
    out_tail[2] = recon;
    out_tail[3] = dagl;
  }
}

// ---------------------------------------------------------------------------
extern "C" void kernel_launch(void* const* d_in, const int* in_sizes, int n_in,
                              void* d_out, int out_size, void* d_ws, size_t ws_size,
                              hipStream_t stream) {
  const float* x      = (const float*)d_in[0];
  const float* enc_w  = (const float*)d_in[1];
  const float* enc_b  = (const float*)d_in[2];
  const float* enc_g  = (const float*)d_in[3];
  const float* enc_bt = (const float*)d_in[4];
  const float* dag_w  = (const float*)d_in[5];
  const float* cw1    = (const float*)d_in[6];
  const float* cb1    = (const float*)d_in[7];
  const float* cg     = (const float*)d_in[8];
  const float* cbt    = (const float*)d_in[9];
  const float* cw2    = (const float*)d_in[10];
  const float* cb2    = (const float*)d_in[11];
  const float* dec_w1 = (const float*)d_in[12];
  const float* dec_b1 = (const float*)d_in[13];
  const float* dec_g  = (const float*)d_in[14];
  const float* dec_bt = (const float*)d_in[15];
  const float* dec_w2 = (const float*)d_in[16];
  const float* dec_b2 = (const float*)d_in[17];

  uint16_t* S    = (uint16_t*)d_ws;                       // [16384x1024] bf16, 32 MiB
  uint16_t* Wbf  = (uint16_t*)((char*)d_ws + (size_t)NTOK * DIM * 2);
  uint16_t* ewb  = Wbf;                                   // enc_w   2,097,152
  uint16_t* d1b  = Wbf + 2097152;                         // dec_w1  1,048,576
  uint16_t* d2b  = Wbf + 3145728;                         // dec_w2  1,048,576
  uint16_t* c1b  = Wbf + 4194304;                         // cw1       65,536
  uint16_t* c2b  = Wbf + 4259840;                         // cw2       65,536

  uint16_t* Obf  = (uint16_t*)d_out;                      // bf16 scratch (lower half)
  float*    O    = (float*)d_out;                         // final fp32 x_recon + losses

  // x_bf16 placement: workspace if it fits (no race with GEMM2's C-writes,
  // enables bf16 recon compare); else d_out upper half (round-14 fallback).
  const size_t XBF2_OFF = (size_t)NTOK * DIM * 2 + (size_t)4325376 * 2;  // 42,205,184
  const bool ws_big = ws_size >= XBF2_OFF + (size_t)NTOK * DIM * 2;      // 75.8 MB
  uint16_t* xbf = ws_big ? (uint16_t*)((char*)d_ws + XBF2_OFF)
                         : (uint16_t*)d_out + (size_t)NOUT_ELEMS;

  // 1. x -> bf16, weights -> bf16, dag/partials init (single launch)
  cvt_all_kernel<<<10305, 256, 0, stream>>>(
      x, xbf, enc_w, dec_w1, dec_w2, cw1, cw2, Wbf, dag_w);

  // 2. encoder GEMM (merged, N=2048, split epilogue): mu -> Obf, lv -> S
  gemm256_kernel<uint16_t, true, 0>
      <<<dim3(64, 8, 1), 512, 0, stream>>>(
      xbf, ewb, enc_b, Obf, S, nullptr, DIM, DIM, DIM, DIM);

  // 3. fused LN + KL + causal: z_causal overwrites mu in Obf
  kl_causal_kernel<<<NTOK / 2, 256, 0, stream>>>(S, Obf, enc_g, enc_bt, dag_w);

  // 4. fused concept transform (concept1 + LN64 + ReLU + concept2), in-place
  concept_fused_kernel<<<dim3(128, 16, 1), 256, 0, stream>>>(
      Obf, c1b, c2b, cb1, cg, cbt, cb2);

  // 5. decoder GEMM1: d_pre = z_t @ dec_w1^T + dec_b1 -> S
  gemm256_kernel<uint16_t, false, 0>
      <<<dim3(64, 4, 1), 512, 0, stream>>>(
      Obf, d1b, dec_b1, S, S, nullptr, DIM, DIM, DIM, DIM);

  // 6. decoder LN + ReLU (in-place on S)
  ln_relu_kernel<<<NTOK / 2, 256, 0, stream>>>(S, dec_g, dec_bt);

  // 7. decoder GEMM2 + fused recon: x_recon = d @ dec_w2^T + dec_b2 -> O (fp32)
  if (ws_big) {
    gemm256_kernel<float, false, 2>
        <<<dim3(64, 4, 1), 512, 0, stream>>>(
        S, d2b, dec_b2, O, O, xbf, DIM, DIM, DIM, DIM);
  } else {
    gemm256_kernel<float, false, 1>
        <<<dim3(64, 4, 1), 512, 0, stream>>>(
        S, d2b, dec_b2, O, O, x, DIM, DIM, DIM, DIM);
  }

  // 8. final scalars
  finalize_kernel<<<1, 256, 0, stream>>>(O + (size_t)NOUT_ELEMS);
}